// Round 1
// baseline (769.356 us; speedup 1.0000x reference)
//
#include <hip/hip_runtime.h>

#define THREADS 256

// ---------------- degree / norm ----------------
__global__ __launch_bounds__(THREADS) void k_deg_init(float* __restrict__ deg, int n) {
    int i = blockIdx.x * THREADS + threadIdx.x;
    if (i < n) deg[i] = 1.0f;   // self-loop contributes 1
}

__global__ __launch_bounds__(THREADS) void k_deg_edges(const int* __restrict__ dst,
                                                       float* __restrict__ deg, int E) {
    int e = blockIdx.x * THREADS + threadIdx.x;
    if (e < E) atomicAdd(&deg[dst[e]], 1.0f);
}

__global__ __launch_bounds__(THREADS) void k_rsqrt(float* __restrict__ deg, int n) {
    int i = blockIdx.x * THREADS + threadIdx.x;
    if (i < n) deg[i] = rsqrtf(deg[i]);   // deg >= 1 always (self-loops)
}

// ---------------- GEMM1: xw[i][f] = (x[i] @ W1)[f] * dinv[i] ----------------
// 16 nodes per block, 256 threads = 16 nodes x 16 feats.
// x tile staged in LDS with row pitch 292 (288 % 32 == 0 would 4-way bank-alias).
__global__ __launch_bounds__(THREADS) void k_gemm1(const float* __restrict__ x,
                                                   const float* __restrict__ W1,
                                                   const float* __restrict__ dinv,
                                                   float* __restrict__ xw, int n) {
    __shared__ float xs[16 * 292];
    __shared__ float wsh[288 * 16];
    const int t = threadIdx.x;
    const int block0 = blockIdx.x * 16;

    for (int i = t; i < 288 * 16; i += THREADS) wsh[i] = W1[i];

    int rows = n - block0; if (rows > 16) rows = 16;
    const float4* x4 = reinterpret_cast<const float4*>(x + (size_t)block0 * 288);
    const int tot4 = rows * 72;                    // 288/4 float4 per row
    for (int i = t; i < tot4; i += THREADS) {
        int r = i / 72, c = i - r * 72;
        *reinterpret_cast<float4*>(&xs[r * 292 + c * 4]) = x4[i];
    }
    __syncthreads();

    const int nl = t >> 4, f = t & 15;
    const int row = block0 + nl;
    if (row < n) {
        float acc = 0.f;
        #pragma unroll 8
        for (int k = 0; k < 288; ++k)
            acc = fmaf(xs[nl * 292 + k], wsh[k * 16 + f], acc);
        xw[(size_t)row * 16 + f] = acc * dinv[row];
    }
}

// ---------------- aggregation (generic over F via template) ----------------
// agg[i][f] starts at self contribution: xw_scaled[i][f] * dinv[i]
// (xw_scaled already carries one dinv factor -> self term = xw * dinv^2)
template <int F>
__global__ __launch_bounds__(THREADS) void k_agg_init(const float* __restrict__ xws,
                                                      const float* __restrict__ dinv,
                                                      float* __restrict__ agg, int n) {
    int t = blockIdx.x * THREADS + threadIdx.x;
    if (t < n * F) agg[t] = xws[t] * dinv[t / F];
}

template <int F>
__global__ __launch_bounds__(THREADS) void k_agg_edges(const int* __restrict__ src,
                                                       const int* __restrict__ dst,
                                                       const float* __restrict__ dinv,
                                                       const float* __restrict__ xws,
                                                       float* __restrict__ agg, int E) {
    int t = blockIdx.x * THREADS + threadIdx.x;
    if (t >= E * F) return;
    int e = t / F, f = t - e * F;
    int s = src[e], d = dst[e];
    float v = xws[(size_t)s * F + f] * dinv[d];
    atomicAdd(&agg[(size_t)d * F + f], v);
}

// ---------------- GEMM2: h[i][f] = relu(agg1[i] + b1) @ W2 * dinv[i] ----------------
__global__ __launch_bounds__(THREADS) void k_gemm2(const float* __restrict__ agg1,
                                                   const float* __restrict__ b1,
                                                   const float* __restrict__ W2,
                                                   const float* __restrict__ dinv,
                                                   float* __restrict__ h, int n) {
    int t = blockIdx.x * THREADS + threadIdx.x;
    if (t >= n * 32) return;
    int node = t >> 5, f = t & 31;
    const float* row = agg1 + (size_t)node * 16;
    float acc = 0.f;
    #pragma unroll
    for (int k = 0; k < 16; ++k) {
        float v = fmaxf(row[k] + b1[k], 0.f);
        acc = fmaf(v, W2[k * 32 + f], acc);
    }
    h[t] = acc * dinv[node];
}

// ---------------- final FC: out[i][o] = relu(agg2[i] + b2) @ Wfc + bfc ----------------
__global__ __launch_bounds__(THREADS) void k_final(const float* __restrict__ agg2,
                                                   const float* __restrict__ b2,
                                                   const float* __restrict__ Wfc,
                                                   const float* __restrict__ bfc,
                                                   float* __restrict__ out, int n) {
    int t = blockIdx.x * THREADS + threadIdx.x;
    if (t >= n * 7) return;
    int node = t / 7, o = t - node * 7;
    const float* row = agg2 + (size_t)node * 32;
    float acc = bfc[o];
    #pragma unroll
    for (int k = 0; k < 32; ++k)
        acc = fmaf(fmaxf(row[k] + b2[k], 0.f), Wfc[k * 7 + o], acc);
    out[t] = acc;
}

extern "C" void kernel_launch(void* const* d_in, const int* in_sizes, int n_in,
                              void* d_out, int out_size, void* d_ws, size_t ws_size,
                              hipStream_t stream) {
    const float* x   = (const float*)d_in[0];
    const int*   ei  = (const int*)d_in[1];
    const float* W1  = (const float*)d_in[2];
    const float* b1  = (const float*)d_in[3];
    const float* W2  = (const float*)d_in[4];
    const float* b2  = (const float*)d_in[5];
    const float* Wfc = (const float*)d_in[6];
    const float* bfc = (const float*)d_in[7];

    const int n = in_sizes[0] / 288;       // 100000
    const int E = in_sizes[1] / 2;         // 3200000
    const int* src = ei;
    const int* dst = ei + E;

    float* ws   = (float*)d_ws;
    float* dinv = ws;                          // n floats (deg -> dinv in place)
    float* buf1 = ws + n;                      // n*32 floats: xw (n*16), later h1W2 (n*32)
    float* buf2 = buf1 + (size_t)n * 32;       // n*32 floats: agg1 (n*16), later agg2 (n*32)
    float* out  = (float*)d_out;

    const int gn = (n + THREADS - 1) / THREADS;

    k_deg_init<<<gn, THREADS, 0, stream>>>(dinv, n);
    k_deg_edges<<<(E + THREADS - 1) / THREADS, THREADS, 0, stream>>>(dst, dinv, E);
    k_rsqrt<<<gn, THREADS, 0, stream>>>(dinv, n);

    k_gemm1<<<(n + 15) / 16, THREADS, 0, stream>>>(x, W1, dinv, buf1, n);

    k_agg_init<16><<<(n * 16 + THREADS - 1) / THREADS, THREADS, 0, stream>>>(buf1, dinv, buf2, n);
    k_agg_edges<16><<<(E * 16 + THREADS - 1) / THREADS + 1, THREADS, 0, stream>>>(src, dst, dinv, buf1, buf2, E);

    k_gemm2<<<(n * 32 + THREADS - 1) / THREADS, THREADS, 0, stream>>>(buf2, b1, W2, dinv, buf1, n);

    k_agg_init<32><<<(n * 32 + THREADS - 1) / THREADS, THREADS, 0, stream>>>(buf1, dinv, buf2, n);
    k_agg_edges<32><<<(E * 32 + THREADS - 1) / THREADS + 1, THREADS, 0, stream>>>(src, dst, dinv, buf1, buf2, E);

    k_final<<<(n * 7 + THREADS - 1) / THREADS, THREADS, 0, stream>>>(buf2, b2, Wfc, bfc, out, n);
}

// Round 2
// 611.745 us; speedup vs baseline: 1.2576x; 1.2576x over previous
//
#include <hip/hip_runtime.h>

#define THREADS 256

// ---------------- CSR build ----------------
__global__ __launch_bounds__(THREADS) void k_zero(int* __restrict__ cnt, int n) {
    int i = blockIdx.x * THREADS + threadIdx.x;
    if (i < n) cnt[i] = 0;
}

__global__ __launch_bounds__(THREADS) void k_count(const int* __restrict__ dst,
                                                   int* __restrict__ cnt, int E) {
    int e = blockIdx.x * THREADS + threadIdx.x;
    if (e < E) atomicAdd(&cnt[dst[e]], 1);
}

// block-level exclusive scan (Hillis-Steele in LDS), emit block sums
__global__ __launch_bounds__(THREADS) void k_scan1(const int* __restrict__ cnt,
                                                   int* __restrict__ off,
                                                   int* __restrict__ bsum, int n) {
    __shared__ int s[THREADS];
    const int tid = threadIdx.x;
    const int i = blockIdx.x * THREADS + tid;
    int v = (i < n) ? cnt[i] : 0;
    int acc = v;
    s[tid] = acc; __syncthreads();
    for (int d = 1; d < THREADS; d <<= 1) {
        int add = (tid >= d) ? s[tid - d] : 0;
        __syncthreads();
        acc += add; s[tid] = acc;
        __syncthreads();
    }
    if (i < n) off[i] = acc - v;                  // exclusive
    if (tid == THREADS - 1) bsum[blockIdx.x] = acc;
}

// scan of block sums (nb <= 512), in place -> exclusive
__global__ __launch_bounds__(512) void k_scan2(int* __restrict__ bsum, int nb) {
    __shared__ int s[512];
    const int tid = threadIdx.x;
    int v = (tid < nb) ? bsum[tid] : 0;
    int acc = v;
    s[tid] = acc; __syncthreads();
    for (int d = 1; d < 512; d <<= 1) {
        int add = (tid >= d) ? s[tid - d] : 0;
        __syncthreads();
        acc += add; s[tid] = acc;
        __syncthreads();
    }
    if (tid < nb) bsum[tid] = acc - v;
}

// add back block offsets; init write pointers; compute dinv = rsqrt(deg+1)
__global__ __launch_bounds__(THREADS) void k_scan3(int* __restrict__ off,
                                                   const int* __restrict__ bsum,
                                                   const int* __restrict__ cnt,
                                                   int* __restrict__ wp,
                                                   float* __restrict__ dinv, int n) {
    int i = blockIdx.x * THREADS + threadIdx.x;
    if (i < n) {
        int o = off[i] + bsum[blockIdx.x];
        off[i] = o;
        wp[i] = o;
        dinv[i] = rsqrtf((float)cnt[i] + 1.0f);   // +1 = self loop
    }
}

__global__ __launch_bounds__(THREADS) void k_fill(const int* __restrict__ src,
                                                  const int* __restrict__ dst,
                                                  int* __restrict__ wp,
                                                  int* __restrict__ csr, int E) {
    int e = blockIdx.x * THREADS + threadIdx.x;
    if (e < E) {
        int pos = atomicAdd(&wp[dst[e]], 1);
        csr[pos] = src[e];
    }
}

// ---------------- GEMM1: xw[i][f] = (x[i] @ W1)[f] * dinv[i] ----------------
__global__ __launch_bounds__(THREADS) void k_gemm1(const float* __restrict__ x,
                                                   const float* __restrict__ W1,
                                                   const float* __restrict__ dinv,
                                                   float* __restrict__ xw, int n) {
    __shared__ float xs[16 * 292];
    __shared__ float wsh[288 * 16];
    const int t = threadIdx.x;
    const int block0 = blockIdx.x * 16;

    for (int i = t; i < 288 * 16; i += THREADS) wsh[i] = W1[i];

    int rows = n - block0; if (rows > 16) rows = 16;
    const float4* x4 = reinterpret_cast<const float4*>(x + (size_t)block0 * 288);
    const int tot4 = rows * 72;
    for (int i = t; i < tot4; i += THREADS) {
        int r = i / 72, c = i - r * 72;
        *reinterpret_cast<float4*>(&xs[r * 292 + c * 4]) = x4[i];
    }
    __syncthreads();

    const int nl = t >> 4, f = t & 15;
    const int row = block0 + nl;
    if (row < n) {
        float acc = 0.f;
        #pragma unroll 8
        for (int k = 0; k < 288; ++k)
            acc = fmaf(xs[nl * 292 + k], wsh[k * 16 + f], acc);
        xw[(size_t)row * 16 + f] = acc * dinv[row];
    }
}

// ---------------- pull aggregation ----------------
// VF = F/4 lanes per node, each lane owns one float4 of the feature row.
// xws rows are pre-scaled by dinv[src]; self-loop = own row; final *dinv[node].
template <int VF>
__global__ __launch_bounds__(THREADS) void k_pull(const float* __restrict__ xws,
                                                  const int* __restrict__ csr,
                                                  const int* __restrict__ off,
                                                  const int* __restrict__ cnt,
                                                  const float* __restrict__ dinv,
                                                  float* __restrict__ outbuf, int n) {
    int t = blockIdx.x * THREADS + threadIdx.x;
    int node = t / VF, q = t - node * VF;
    if (node >= n) return;
    const float4* x4 = reinterpret_cast<const float4*>(xws);
    float4 acc = x4[(size_t)node * VF + q];       // self loop
    int beg = off[node], end = beg + cnt[node];
    for (int j = beg; j < end; ++j) {
        int s = csr[j];
        float4 v = x4[(size_t)s * VF + q];
        acc.x += v.x; acc.y += v.y; acc.z += v.z; acc.w += v.w;
    }
    float dv = dinv[node];
    acc.x *= dv; acc.y *= dv; acc.z *= dv; acc.w *= dv;
    reinterpret_cast<float4*>(outbuf)[(size_t)node * VF + q] = acc;
}

// ---------------- GEMM2: h[i][f] = relu(agg1[i] + b1) @ W2 * dinv[i] ----------------
__global__ __launch_bounds__(THREADS) void k_gemm2(const float* __restrict__ agg1,
                                                   const float* __restrict__ b1,
                                                   const float* __restrict__ W2,
                                                   const float* __restrict__ dinv,
                                                   float* __restrict__ h, int n) {
    int t = blockIdx.x * THREADS + threadIdx.x;
    if (t >= n * 32) return;
    int node = t >> 5, f = t & 31;
    const float* row = agg1 + (size_t)node * 16;
    float acc = 0.f;
    #pragma unroll
    for (int k = 0; k < 16; ++k) {
        float v = fmaxf(row[k] + b1[k], 0.f);
        acc = fmaf(v, W2[k * 32 + f], acc);
    }
    h[t] = acc * dinv[node];
}

// ---------------- final FC ----------------
__global__ __launch_bounds__(THREADS) void k_final(const float* __restrict__ agg2,
                                                   const float* __restrict__ b2,
                                                   const float* __restrict__ Wfc,
                                                   const float* __restrict__ bfc,
                                                   float* __restrict__ out, int n) {
    int t = blockIdx.x * THREADS + threadIdx.x;
    if (t >= n * 7) return;
    int node = t / 7, o = t - node * 7;
    const float* row = agg2 + (size_t)node * 32;
    float acc = bfc[o];
    #pragma unroll
    for (int k = 0; k < 32; ++k)
        acc = fmaf(fmaxf(row[k] + b2[k], 0.f), Wfc[k * 7 + o], acc);
    out[t] = acc;
}

extern "C" void kernel_launch(void* const* d_in, const int* in_sizes, int n_in,
                              void* d_out, int out_size, void* d_ws, size_t ws_size,
                              hipStream_t stream) {
    const float* x   = (const float*)d_in[0];
    const int*   ei  = (const int*)d_in[1];
    const float* W1  = (const float*)d_in[2];
    const float* b1  = (const float*)d_in[3];
    const float* W2  = (const float*)d_in[4];
    const float* b2  = (const float*)d_in[5];
    const float* Wfc = (const float*)d_in[6];
    const float* bfc = (const float*)d_in[7];

    const int n = in_sizes[0] / 288;       // 100000
    const int E = in_sizes[1] / 2;         // 3200000
    const int* src = ei;
    const int* dst = ei + E;

    auto align4 = [](size_t v) { return (v + 3) & ~(size_t)3; };  // 16B-align (elements)
    int*   wsI  = (int*)d_ws;
    size_t p = 0;
    int*   cnt  = wsI + p;  p += align4(n);
    int*   off  = wsI + p;  p += align4(n);
    int*   wp   = wsI + p;  p += align4(n);
    int*   bsum = wsI + p;  p += 512;
    int*   csr  = wsI + p;  p += align4(E);
    float* dinv = (float*)(wsI + p);  p += align4(n);
    float* buf1 = (float*)(wsI + p);  p += align4((size_t)n * 32);
    float* buf2 = (float*)(wsI + p);
    float* out  = (float*)d_out;

    const int gn = (n + THREADS - 1) / THREADS;   // 391 blocks
    const int gE = (E + THREADS - 1) / THREADS;

    k_zero <<<gn, THREADS, 0, stream>>>(cnt, n);
    k_count<<<gE, THREADS, 0, stream>>>(dst, cnt, E);
    k_scan1<<<gn, THREADS, 0, stream>>>(cnt, off, bsum, n);
    k_scan2<<<1, 512, 0, stream>>>(bsum, gn);
    k_scan3<<<gn, THREADS, 0, stream>>>(off, bsum, cnt, wp, dinv, n);
    k_fill <<<gE, THREADS, 0, stream>>>(src, dst, wp, csr, E);

    k_gemm1<<<(n + 15) / 16, THREADS, 0, stream>>>(x, W1, dinv, buf1, n);

    k_pull<4><<<((size_t)n * 4 + THREADS - 1) / THREADS, THREADS, 0, stream>>>(
        buf1, csr, off, cnt, dinv, buf2, n);

    k_gemm2<<<((size_t)n * 32 + THREADS - 1) / THREADS, THREADS, 0, stream>>>(
        buf2, b1, W2, dinv, buf1, n);

    k_pull<8><<<((size_t)n * 8 + THREADS - 1) / THREADS, THREADS, 0, stream>>>(
        buf1, csr, off, cnt, dinv, buf2, n);

    k_final<<<((size_t)n * 7 + THREADS - 1) / THREADS, THREADS, 0, stream>>>(
        buf2, b2, Wfc, bfc, out, n);
}